// Round 5
// baseline (45.236 us; speedup 1.0000x reference)
//
#include <hip/hip_runtime.h>
#include <math.h>

#define N_TOKENS 32768
#define D_MODEL  1024
#define N_EXPERT 16
#define T        16               // tokens per block
#define NBLK     (N_TOKENS / T)   // 2048

// d_out layout (float32, concatenated outputs):
//   [0, 65536)       top_k_indices as floats, row-major [N,2]
//   [65536, 131072)  top_k_scores,            row-major [N,2]
//   [131072]         loss scalar
// d_ws: NBLK slots of 32 floats; slot b: [0..15] expert counts, [16..31] prob sums.
//       Every slot is fully written by its block each call -> no zero-init needed.

__global__ __launch_bounds__(256, 3)
void gate_kernel(const float* __restrict__ inp,
                 const float* __restrict__ W,
                 float* __restrict__ out,
                 float* __restrict__ ws)
{
    const int tid  = threadIdx.x;
    const int wave = tid >> 6;
    const int lane = tid & 63;
    const int d0   = wave * 256 + lane * 4;   // this lane's 4 dims
    const int tok0 = blockIdx.x * T;
    const bool hi8 = (lane & 8) != 0;
    const bool hi4 = (lane & 4) != 0;
    const bool hi2 = (lane & 2) != 0;
    const bool hi1 = (lane & 1) != 0;

    // W fragment: W[e][d0..d0+3] for all 16 experts = 64 VGPRs, loaded once.
    float4 wreg[N_EXPERT];
    #pragma unroll
    for (int e = 0; e < N_EXPERT; ++e)
        wreg[e] = *reinterpret_cast<const float4*>(W + e * D_MODEL + d0);

    __shared__ float lds_part[T][4][N_EXPERT];   // [token][wave][expert]
    __shared__ float lds_cnt[T][N_EXPERT];
    __shared__ float lds_ps[T][N_EXPERT];

    const float* xptr = inp + (size_t)tok0 * D_MODEL + d0;

#define LOADX(xr, t) xr = *reinterpret_cast<const float4*>(xptr + (t) * D_MODEL);

#define DOT(xv, e) (xv.x*wreg[e].x + xv.y*wreg[e].y + xv.z*wreg[e].z + xv.w*wreg[e].w)

    // Transpose-reduce with named scalars only (no private arrays -> no scratch).
    // After masks 8,4,2,1,16,32: s0 = full 256-dim wave partial of expert (lane&15).
#define DOTOK(xv, t) do { \
    float a0 =DOT(xv,0),  a1 =DOT(xv,1),  a2 =DOT(xv,2),  a3 =DOT(xv,3);  \
    float a4 =DOT(xv,4),  a5 =DOT(xv,5),  a6 =DOT(xv,6),  a7 =DOT(xv,7);  \
    float a8 =DOT(xv,8),  a9 =DOT(xv,9),  a10=DOT(xv,10), a11=DOT(xv,11); \
    float a12=DOT(xv,12), a13=DOT(xv,13), a14=DOT(xv,14), a15=DOT(xv,15); \
    float b0 = (hi8 ? a8  : a0) + __shfl_xor(hi8 ? a0 : a8 , 8); \
    float b1 = (hi8 ? a9  : a1) + __shfl_xor(hi8 ? a1 : a9 , 8); \
    float b2 = (hi8 ? a10 : a2) + __shfl_xor(hi8 ? a2 : a10, 8); \
    float b3 = (hi8 ? a11 : a3) + __shfl_xor(hi8 ? a3 : a11, 8); \
    float b4 = (hi8 ? a12 : a4) + __shfl_xor(hi8 ? a4 : a12, 8); \
    float b5 = (hi8 ? a13 : a5) + __shfl_xor(hi8 ? a5 : a13, 8); \
    float b6 = (hi8 ? a14 : a6) + __shfl_xor(hi8 ? a6 : a14, 8); \
    float b7 = (hi8 ? a15 : a7) + __shfl_xor(hi8 ? a7 : a15, 8); \
    float c0 = (hi4 ? b4 : b0) + __shfl_xor(hi4 ? b0 : b4, 4); \
    float c1 = (hi4 ? b5 : b1) + __shfl_xor(hi4 ? b1 : b5, 4); \
    float c2 = (hi4 ? b6 : b2) + __shfl_xor(hi4 ? b2 : b6, 4); \
    float c3 = (hi4 ? b7 : b3) + __shfl_xor(hi4 ? b3 : b7, 4); \
    float e0 = (hi2 ? c2 : c0) + __shfl_xor(hi2 ? c0 : c2, 2); \
    float e1 = (hi2 ? c3 : c1) + __shfl_xor(hi2 ? c1 : c3, 2); \
    float s0 = (hi1 ? e1 : e0) + __shfl_xor(hi1 ? e0 : e1, 1); \
    s0 += __shfl_xor(s0, 16); \
    s0 += __shfl_xor(s0, 32); \
    if (lane < N_EXPERT) lds_part[t][wave][lane] = s0; \
} while (0)

    // Software pipeline: 4 named prefetch regs, distance 4 tokens.
    float4 x0, x1, x2, x3;
    LOADX(x0, 0) LOADX(x1, 1) LOADX(x2, 2) LOADX(x3, 3)
    for (int g = 0; g < 3; ++g) {
        const int tb = g * 4;
        DOTOK(x0, tb + 0); LOADX(x0, tb + 4)
        DOTOK(x1, tb + 1); LOADX(x1, tb + 5)
        DOTOK(x2, tb + 2); LOADX(x2, tb + 6)
        DOTOK(x3, tb + 3); LOADX(x3, tb + 7)
    }
    DOTOK(x0, 12); DOTOK(x1, 13); DOTOK(x2, 14); DOTOK(x3, 15);

    __syncthreads();

    // Phase B: 16 tokens x 16 expert-lanes: sum 4 wave partials, top-2
    // merge butterfly ((val desc, idx asc) == jax.lax.top_k), 2-way softmax.
    {
        const int tgrp = tid >> 4;
        const int el   = tid & 15;
        float v1 = lds_part[tgrp][0][el] + lds_part[tgrp][1][el]
                 + lds_part[tgrp][2][el] + lds_part[tgrp][3][el];
        int   i1 = el;
        float v2 = -INFINITY;
        int   i2 = 0;
        #pragma unroll
        for (int m = 1; m <= 8; m <<= 1) {
            float o1 = __shfl_xor(v1, m);
            int  oi1 = __shfl_xor(i1, m);
            float o2 = __shfl_xor(v2, m);
            int  oi2 = __shfl_xor(i2, m);
            bool afirst = (v1 > o1) || (v1 == o1 && i1 < oi1);
            float c1v = afirst ? v1 : o1;   int c1i = afirst ? i1 : oi1;
            float bv  = afirst ? o1 : v1;   int bi  = afirst ? oi1 : i1;
            float sv  = afirst ? v2 : o2;   int si  = afirst ? i2 : oi2;
            bool sgt  = (bv > sv) || (bv == sv && bi < si);
            v1 = c1v; i1 = c1i;
            v2 = sgt ? bv : sv;  i2 = sgt ? bi : si;
        }
        float tt = expf(v2 - v1);
        float p1 = 1.f / (1.f + tt);
        float p2 = tt * p1;
        const int tok = tok0 + tgrp;
        if (el == 0) {
            *reinterpret_cast<float2*>(out + 2 * tok) =
                make_float2((float)i1, (float)i2);
            *reinterpret_cast<float2*>(out + 2 * N_TOKENS + 2 * tok) =
                make_float2(p1, p2);
        }
        lds_cnt[tgrp][el] = (el == i1 ? 1.f : 0.f) + (el == i2 ? 1.f : 0.f);
        lds_ps [tgrp][el] = (el == i1 ? p1 : 0.f) + (el == i2 ? p2 : 0.f);
    }
    __syncthreads();

    // Block-level reduce; plain stores to this block's private ws slot.
    if (tid < 32) {
        const int el = tid & 15;
        float ssum = 0.f;
        if (tid < 16) {
            #pragma unroll
            for (int g = 0; g < T; ++g) ssum += lds_cnt[g][el];
        } else {
            #pragma unroll
            for (int g = 0; g < T; ++g) ssum += lds_ps[g][el];
        }
        ws[blockIdx.x * 32 + tid] = ssum;
    }
#undef LOADX
#undef DOT
#undef DOTOK
}

__global__ void loss_kernel(const float* __restrict__ ws, float* __restrict__ out)
{
    // Reduce NBLK x 32 partial slots, then dot counts x prob-sums.
    __shared__ float partial[8][32];
    __shared__ float col[32];
    const int tid = threadIdx.x;   // 256
    const int c   = tid & 31;
    const int ch  = tid >> 5;      // 0..7
    float s = 0.f;
    for (int b = 0; b < NBLK / 8; ++b)
        s += ws[(size_t)(ch * (NBLK / 8) + b) * 32 + c];
    partial[ch][c] = s;
    __syncthreads();
    if (tid < 32) {
        float t = 0.f;
        #pragma unroll
        for (int k = 0; k < 8; ++k) t += partial[k][tid];
        col[tid] = t;
    }
    __syncthreads();
    if (tid == 0) {
        float sum = 0.f;
        #pragma unroll
        for (int e = 0; e < N_EXPERT; ++e)
            sum += col[e] * col[16 + e];
        out[4 * N_TOKENS] = sum * (float)N_EXPERT
                          / ((float)N_TOKENS * (float)N_TOKENS);
    }
}

extern "C" void kernel_launch(void* const* d_in, const int* in_sizes, int n_in,
                              void* d_out, int out_size, void* d_ws, size_t ws_size,
                              hipStream_t stream)
{
    const float* inp = (const float*)d_in[0];
    const float* W   = (const float*)d_in[1];
    float* out = (float*)d_out;
    float* ws  = (float*)d_ws;

    gate_kernel<<<NBLK, 256, 0, stream>>>(inp, W, out, ws);
    loss_kernel<<<1, 256, 0, stream>>>(ws, out);
}

// Round 6
// 42.710 us; speedup vs baseline: 1.0591x; 1.0591x over previous
//
#include <hip/hip_runtime.h>
#include <math.h>

#define N_TOKENS 32768
#define D_MODEL  1024
#define N_EXPERT 16
#define T        16               // tokens per block
#define NBLK     (N_TOKENS / T)   // 2048

typedef float f32x4 __attribute__((ext_vector_type(4)));
typedef float f32x2 __attribute__((ext_vector_type(2)));

// DPP cross-lane XOR within 16-lane rows (VALU pipe, no lgkmcnt):
//   mask1: quad_perm [1,0,3,2] = 0xB1; mask2: quad_perm [2,3,0,1] = 0x4E;
//   mask8: row_ror:8 = 0x128  ((i+8) mod 16 == i^8).
template<int CTRL>
static __device__ __forceinline__ float dpp_xor(float v) {
    return __int_as_float(__builtin_amdgcn_update_dpp(
        0, __float_as_int(v), CTRL, 0xF, 0xF, true));
}

// Packed fp32 dot over 4 dims: v_pk_mul + v_pk_fma + horizontal add.
static __device__ __forceinline__ float dot4pk(f32x4 x, f32x4 w) {
    f32x2 xl = __builtin_shufflevector(x, x, 0, 1);
    f32x2 xh = __builtin_shufflevector(x, x, 2, 3);
    f32x2 wl = __builtin_shufflevector(w, w, 0, 1);
    f32x2 wh = __builtin_shufflevector(w, w, 2, 3);
    f32x2 m, r;
    asm("v_pk_mul_f32 %0, %1, %2" : "=v"(m) : "v"(xl), "v"(wl));
    asm("v_pk_fma_f32 %0, %1, %2, %3" : "=v"(r) : "v"(xh), "v"(wh), "v"(m));
    return r.x + r.y;
}

// d_out layout (float32, concatenated outputs):
//   [0, 65536)       top_k_indices as floats, row-major [N,2]
//   [65536, 131072)  top_k_scores,            row-major [N,2]
//   [131072]         loss scalar
// d_ws: NBLK slots of 32 floats; slot b: [0..15] expert counts, [16..31] prob sums.

__global__ __launch_bounds__(256, 3)
void gate_kernel(const float* __restrict__ inp,
                 const float* __restrict__ W,
                 float* __restrict__ out,
                 float* __restrict__ ws)
{
    const int tid  = threadIdx.x;
    const int wave = tid >> 6;
    const int lane = tid & 63;
    const int d0   = wave * 256 + lane * 4;   // this lane's 4 dims
    const int tok0 = blockIdx.x * T;
    const bool hi8 = (lane & 8) != 0;
    const bool hi4 = (lane & 4) != 0;
    const bool hi2 = (lane & 2) != 0;
    const bool hi1 = (lane & 1) != 0;

    // W fragment: W[e][d0..d0+3] for all 16 experts = 64 VGPRs, loaded once.
    f32x4 wreg[N_EXPERT];
    #pragma unroll
    for (int e = 0; e < N_EXPERT; ++e)
        wreg[e] = *reinterpret_cast<const f32x4*>(W + e * D_MODEL + d0);

    __shared__ float lds_part[T][4][N_EXPERT];   // [token][wave][expert]
    __shared__ float lds_cnt[T][N_EXPERT];
    __shared__ float lds_ps[T][N_EXPERT];

    const float* xptr = inp + (size_t)tok0 * D_MODEL + d0;

#define LOADX(xr, t) xr = *reinterpret_cast<const f32x4*>(xptr + (t) * D_MODEL);

    // Transpose-reduce, named scalars only. Masks 8,2,1 via DPP (VALU pipe);
    // masks 4,16,32 via shfl. After all: s0 = 256-dim wave partial of expert
    // (lane&15).
#define DOTOK(xv, t) do { \
    float a0 =dot4pk(xv,wreg[0]),  a1 =dot4pk(xv,wreg[1]);  \
    float a2 =dot4pk(xv,wreg[2]),  a3 =dot4pk(xv,wreg[3]);  \
    float a4 =dot4pk(xv,wreg[4]),  a5 =dot4pk(xv,wreg[5]);  \
    float a6 =dot4pk(xv,wreg[6]),  a7 =dot4pk(xv,wreg[7]);  \
    float a8 =dot4pk(xv,wreg[8]),  a9 =dot4pk(xv,wreg[9]);  \
    float a10=dot4pk(xv,wreg[10]), a11=dot4pk(xv,wreg[11]); \
    float a12=dot4pk(xv,wreg[12]), a13=dot4pk(xv,wreg[13]); \
    float a14=dot4pk(xv,wreg[14]), a15=dot4pk(xv,wreg[15]); \
    float b0 = (hi8 ? a8  : a0) + dpp_xor<0x128>(hi8 ? a0 : a8 ); \
    float b1 = (hi8 ? a9  : a1) + dpp_xor<0x128>(hi8 ? a1 : a9 ); \
    float b2 = (hi8 ? a10 : a2) + dpp_xor<0x128>(hi8 ? a2 : a10); \
    float b3 = (hi8 ? a11 : a3) + dpp_xor<0x128>(hi8 ? a3 : a11); \
    float b4 = (hi8 ? a12 : a4) + dpp_xor<0x128>(hi8 ? a4 : a12); \
    float b5 = (hi8 ? a13 : a5) + dpp_xor<0x128>(hi8 ? a5 : a13); \
    float b6 = (hi8 ? a14 : a6) + dpp_xor<0x128>(hi8 ? a6 : a14); \
    float b7 = (hi8 ? a15 : a7) + dpp_xor<0x128>(hi8 ? a7 : a15); \
    float c0 = (hi4 ? b4 : b0) + __shfl_xor(hi4 ? b0 : b4, 4); \
    float c1 = (hi4 ? b5 : b1) + __shfl_xor(hi4 ? b1 : b5, 4); \
    float c2 = (hi4 ? b6 : b2) + __shfl_xor(hi4 ? b2 : b6, 4); \
    float c3 = (hi4 ? b7 : b3) + __shfl_xor(hi4 ? b3 : b7, 4); \
    float e0 = (hi2 ? c2 : c0) + dpp_xor<0x4E>(hi2 ? c0 : c2); \
    float e1 = (hi2 ? c3 : c1) + dpp_xor<0x4E>(hi2 ? c1 : c3); \
    float s0 = (hi1 ? e1 : e0) + dpp_xor<0xB1>(hi1 ? e0 : e1); \
    s0 += __shfl_xor(s0, 16); \
    s0 += __shfl_xor(s0, 32); \
    if (lane < N_EXPERT) lds_part[t][wave][lane] = s0; \
} while (0)

    // Software pipeline: 4 named prefetch regs, distance 4 tokens.
    f32x4 x0, x1, x2, x3;
    LOADX(x0, 0) LOADX(x1, 1) LOADX(x2, 2) LOADX(x3, 3)
    for (int g = 0; g < 3; ++g) {
        const int tb = g * 4;
        DOTOK(x0, tb + 0); LOADX(x0, tb + 4)
        DOTOK(x1, tb + 1); LOADX(x1, tb + 5)
        DOTOK(x2, tb + 2); LOADX(x2, tb + 6)
        DOTOK(x3, tb + 3); LOADX(x3, tb + 7)
    }
    DOTOK(x0, 12); DOTOK(x1, 13); DOTOK(x2, 14); DOTOK(x3, 15);

    __syncthreads();

    // Phase B: 16 tokens x 16 expert-lanes: sum 4 wave partials, top-2
    // merge butterfly ((val desc, idx asc) == jax.lax.top_k), 2-way softmax.
    {
        const int tgrp = tid >> 4;
        const int el   = tid & 15;
        float v1 = lds_part[tgrp][0][el] + lds_part[tgrp][1][el]
                 + lds_part[tgrp][2][el] + lds_part[tgrp][3][el];
        int   i1 = el;
        float v2 = -INFINITY;
        int   i2 = 0;
        #pragma unroll
        for (int m = 1; m <= 8; m <<= 1) {
            float o1 = __shfl_xor(v1, m);
            int  oi1 = __shfl_xor(i1, m);
            float o2 = __shfl_xor(v2, m);
            int  oi2 = __shfl_xor(i2, m);
            bool afirst = (v1 > o1) || (v1 == o1 && i1 < oi1);
            float c1v = afirst ? v1 : o1;   int c1i = afirst ? i1 : oi1;
            float bv  = afirst ? o1 : v1;   int bi  = afirst ? oi1 : i1;
            float sv  = afirst ? v2 : o2;   int si  = afirst ? i2 : oi2;
            bool sgt  = (bv > sv) || (bv == sv && bi < si);
            v1 = c1v; i1 = c1i;
            v2 = sgt ? bv : sv;  i2 = sgt ? bi : si;
        }
        float tt = expf(v2 - v1);
        float p1 = 1.f / (1.f + tt);
        float p2 = tt * p1;
        const int tok = tok0 + tgrp;
        if (el == 0) {
            *reinterpret_cast<float2*>(out + 2 * tok) =
                make_float2((float)i1, (float)i2);
            *reinterpret_cast<float2*>(out + 2 * N_TOKENS + 2 * tok) =
                make_float2(p1, p2);
        }
        lds_cnt[tgrp][el] = (el == i1 ? 1.f : 0.f) + (el == i2 ? 1.f : 0.f);
        lds_ps [tgrp][el] = (el == i1 ? p1 : 0.f) + (el == i2 ? p2 : 0.f);
    }
    __syncthreads();

    // Block-level reduce; plain stores to this block's private ws slot.
    if (tid < 32) {
        const int el = tid & 15;
        float ssum = 0.f;
        if (tid < 16) {
            #pragma unroll
            for (int g = 0; g < T; ++g) ssum += lds_cnt[g][el];
        } else {
            #pragma unroll
            for (int g = 0; g < T; ++g) ssum += lds_ps[g][el];
        }
        ws[blockIdx.x * 32 + tid] = ssum;
    }
#undef LOADX
#undef DOTOK
}

__global__ void loss_kernel(const float* __restrict__ ws, float* __restrict__ out)
{
    // Reduce NBLK x 32 partial slots, then dot counts x prob-sums.
    __shared__ float partial[8][32];
    __shared__ float col[32];
    const int tid = threadIdx.x;   // 256
    const int c   = tid & 31;
    const int ch  = tid >> 5;      // 0..7
    float s = 0.f;
    for (int b = 0; b < NBLK / 8; ++b)
        s += ws[(size_t)(ch * (NBLK / 8) + b) * 32 + c];
    partial[ch][c] = s;
    __syncthreads();
    if (tid < 32) {
        float t = 0.f;
        #pragma unroll
        for (int k = 0; k < 8; ++k) t += partial[k][tid];
        col[tid] = t;
    }
    __syncthreads();
    if (tid == 0) {
        float sum = 0.f;
        #pragma unroll
        for (int e = 0; e < N_EXPERT; ++e)
            sum += col[e] * col[16 + e];
        out[4 * N_TOKENS] = sum * (float)N_EXPERT
                          / ((float)N_TOKENS * (float)N_TOKENS);
    }
}

extern "C" void kernel_launch(void* const* d_in, const int* in_sizes, int n_in,
                              void* d_out, int out_size, void* d_ws, size_t ws_size,
                              hipStream_t stream)
{
    const float* inp = (const float*)d_in[0];
    const float* W   = (const float*)d_in[1];
    float* out = (float*)d_out;
    float* ws  = (float*)d_ws;

    gate_kernel<<<NBLK, 256, 0, stream>>>(inp, W, out, ws);
    loss_kernel<<<1, 256, 0, stream>>>(ws, out);
}

// Round 7
// 39.010 us; speedup vs baseline: 1.1596x; 1.0948x over previous
//
#include <hip/hip_runtime.h>
#include <math.h>

#define N_TOKENS 32768
#define D_MODEL  1024
#define N_EXPERT 16
#define TPB      256
#define NBLK     512               // blocks
#define TOKS     64                // tokens per block
#define BATCH    16                // tokens per batch (4 batches)

typedef float f32x4 __attribute__((ext_vector_type(4)));
typedef float f32x2 __attribute__((ext_vector_type(2)));

// DPP cross-lane XOR within 16-lane rows (VALU pipe):
//   ^1: quad_perm [1,0,3,2]=0xB1; ^2: quad_perm [2,3,0,1]=0x4E;
//   ^8: row_ror:8 = 0x128 ((i+8) mod 16 == i^8).  (HW-verified round 6.)
template<int CTRL>
static __device__ __forceinline__ float dpp_xor(float v) {
    return __int_as_float(__builtin_amdgcn_update_dpp(
        0, __float_as_int(v), CTRL, 0xF, 0xF, true));
}

// Packed fp32 dot over 4 dims: v_pk_mul + v_pk_fma + horizontal add.
static __device__ __forceinline__ float dot4pk(f32x4 x, f32x4 w) {
    f32x2 xl = __builtin_shufflevector(x, x, 0, 1);
    f32x2 xh = __builtin_shufflevector(x, x, 2, 3);
    f32x2 wl = __builtin_shufflevector(w, w, 0, 1);
    f32x2 wh = __builtin_shufflevector(w, w, 2, 3);
    f32x2 m, r;
    asm("v_pk_mul_f32 %0, %1, %2" : "=v"(m) : "v"(xl), "v"(wl));
    asm("v_pk_fma_f32 %0, %1, %2, %3" : "=v"(r) : "v"(xh), "v"(wh), "v"(m));
    return r.x + r.y;
}

// d_out layout (float32, concatenated outputs):
//   [0, 65536)       top_k_indices as floats, row-major [N,2]
//   [65536, 131072)  top_k_scores,            row-major [N,2]
//   [131072]         loss scalar
// d_ws: NBLK slots of 32 floats; slot b: [0..15] expert counts, [16..31] prob sums.

__global__ __launch_bounds__(256, 3)
void gate_kernel(const float* __restrict__ inp,
                 const float* __restrict__ W,
                 float* __restrict__ out,
                 float* __restrict__ ws)
{
    const int tid  = threadIdx.x;
    const int wave = tid >> 6;
    const int lane = tid & 63;
    const int p    = lane & 15;               // expert rotation for this lane
    const int d0   = wave * 256 + lane * 4;   // this lane's 4 dims
    const int base = blockIdx.x * TOKS;

    // XOR-rotated W fragment: wreg[j] = W[j^p][d0..d0+3].  After the uniform
    // butterfly, lane ends holding expert p's logit partial.  64 VGPRs.
    f32x4 wreg[N_EXPERT];
    #pragma unroll
    for (int j = 0; j < N_EXPERT; ++j)
        wreg[j] = *reinterpret_cast<const f32x4*>(W + (j ^ p) * D_MODEL + d0);

    __shared__ float lds_part[2][BATCH][4][N_EXPERT];  // double-buffered
    __shared__ float lds_red[4][2][N_EXPERT];          // final cnt/ps reduce

    float cnt_acc = 0.f;   // phase-B per-thread accumulators across batches
    float ps_acc  = 0.f;

#define LOADX(xr, t) xr = *reinterpret_cast<const f32x4*>(xptr + (t) * D_MODEL);

    // Select-free transpose-reduce: stage m does b[j] = a[j] + xor_m(a[j^m]).
    // Masks 8,2,1 via DPP; masks 4,16,32 via shfl (DS pipe, balances load).
#define DOTOK(xv, t, BUF) do { \
    float a0 =dot4pk(xv,wreg[0]),  a1 =dot4pk(xv,wreg[1]);  \
    float a2 =dot4pk(xv,wreg[2]),  a3 =dot4pk(xv,wreg[3]);  \
    float a4 =dot4pk(xv,wreg[4]),  a5 =dot4pk(xv,wreg[5]);  \
    float a6 =dot4pk(xv,wreg[6]),  a7 =dot4pk(xv,wreg[7]);  \
    float a8 =dot4pk(xv,wreg[8]),  a9 =dot4pk(xv,wreg[9]);  \
    float a10=dot4pk(xv,wreg[10]), a11=dot4pk(xv,wreg[11]); \
    float a12=dot4pk(xv,wreg[12]), a13=dot4pk(xv,wreg[13]); \
    float a14=dot4pk(xv,wreg[14]), a15=dot4pk(xv,wreg[15]); \
    float b0 = a0 + dpp_xor<0x128>(a8);  \
    float b1 = a1 + dpp_xor<0x128>(a9);  \
    float b2 = a2 + dpp_xor<0x128>(a10); \
    float b3 = a3 + dpp_xor<0x128>(a11); \
    float b4 = a4 + dpp_xor<0x128>(a12); \
    float b5 = a5 + dpp_xor<0x128>(a13); \
    float b6 = a6 + dpp_xor<0x128>(a14); \
    float b7 = a7 + dpp_xor<0x128>(a15); \
    float c0 = b0 + __shfl_xor(b4, 4); \
    float c1 = b1 + __shfl_xor(b5, 4); \
    float c2 = b2 + __shfl_xor(b6, 4); \
    float c3 = b3 + __shfl_xor(b7, 4); \
    float d0_ = c0 + dpp_xor<0x4E>(c2); \
    float d1_ = c1 + dpp_xor<0x4E>(c3); \
    float s0  = d0_ + dpp_xor<0xB1>(d1_); \
    s0 += __shfl_xor(s0, 16); \
    s0 += __shfl_xor(s0, 32); \
    if (lane < N_EXPERT) BUF[t][wave][lane] = s0; \
} while (0)

    for (int b = 0; b < TOKS / BATCH; ++b) {
        const int tb0 = base + b * BATCH;
        const float* xptr = inp + (size_t)tb0 * D_MODEL + d0;
        float (*buf)[4][N_EXPERT] = lds_part[b & 1];

        // Phase A: 16 tokens, 4-reg software pipeline, no barriers inside.
        f32x4 x0, x1, x2, x3;
        LOADX(x0, 0) LOADX(x1, 1) LOADX(x2, 2) LOADX(x3, 3)
        for (int g = 0; g < 3; ++g) {
            const int t = g * 4;
            DOTOK(x0, t + 0, buf); LOADX(x0, t + 4)
            DOTOK(x1, t + 1, buf); LOADX(x1, t + 5)
            DOTOK(x2, t + 2, buf); LOADX(x2, t + 6)
            DOTOK(x3, t + 3, buf); LOADX(x3, t + 7)
        }
        DOTOK(x0, 12, buf); DOTOK(x1, 13, buf);
        DOTOK(x2, 14, buf); DOTOK(x3, 15, buf);

        __syncthreads();   // buf[b&1] complete; also protects buf[(b+1)&1] reuse

        // Phase B: 16 tokens x 16 expert-lanes: sum 4 wave partials, top-2
        // merge butterfly ((val desc, idx asc) == jax.lax.top_k), softmax.
        {
            const int tgrp = tid >> 4;
            const int el   = tid & 15;
            float v1 = buf[tgrp][0][el] + buf[tgrp][1][el]
                     + buf[tgrp][2][el] + buf[tgrp][3][el];
            int   i1 = el;
            float v2 = -INFINITY;
            int   i2 = 0;
            #pragma unroll
            for (int m = 1; m <= 8; m <<= 1) {
                float o1 = __shfl_xor(v1, m);
                int  oi1 = __shfl_xor(i1, m);
                float o2 = __shfl_xor(v2, m);
                int  oi2 = __shfl_xor(i2, m);
                bool afirst = (v1 > o1) || (v1 == o1 && i1 < oi1);
                float c1v = afirst ? v1 : o1;   int c1i = afirst ? i1 : oi1;
                float bv  = afirst ? o1 : v1;   int bi  = afirst ? oi1 : i1;
                float sv  = afirst ? v2 : o2;   int si  = afirst ? i2 : oi2;
                bool sgt  = (bv > sv) || (bv == sv && bi < si);
                v1 = c1v; i1 = c1i;
                v2 = sgt ? bv : sv;  i2 = sgt ? bi : si;
            }
            float tt = expf(v2 - v1);
            float p1 = 1.f / (1.f + tt);
            float p2 = tt * p1;
            const int tok = tb0 + tgrp;
            if (el == 0) {
                *reinterpret_cast<float2*>(out + 2 * tok) =
                    make_float2((float)i1, (float)i2);
                *reinterpret_cast<float2*>(out + 2 * N_TOKENS + 2 * tok) =
                    make_float2(p1, p2);
            }
            cnt_acc += (el == i1 ? 1.f : 0.f) + (el == i2 ? 1.f : 0.f);
            ps_acc  += (el == i1 ? p1  : 0.f) + (el == i2 ? p2  : 0.f);
        }
        // no second barrier: next phase A writes the other lds buffer
    }

    // Final cnt/ps reduction: lanes l, l^16, l^32 share el -> 2 shuffles,
    // then one cross-wave LDS pass.
    cnt_acc += __shfl_xor(cnt_acc, 16); cnt_acc += __shfl_xor(cnt_acc, 32);
    ps_acc  += __shfl_xor(ps_acc, 16);  ps_acc  += __shfl_xor(ps_acc, 32);
    if (lane < N_EXPERT) {
        lds_red[wave][0][lane] = cnt_acc;
        lds_red[wave][1][lane] = ps_acc;
    }
    __syncthreads();
    if (tid < 32) {
        const int el = tid & 15;
        const int which = tid >> 4;   // 0 = cnt, 1 = ps
        float v = lds_red[0][which][el] + lds_red[1][which][el]
                + lds_red[2][which][el] + lds_red[3][which][el];
        ws[blockIdx.x * 32 + tid] = v;
    }
#undef LOADX
#undef DOTOK
}

__global__ void loss_kernel(const float* __restrict__ ws, float* __restrict__ out)
{
    // Reduce NBLK x 32 partial slots, then dot counts x prob-sums.
    __shared__ float partial[8][32];
    __shared__ float col[32];
    const int tid = threadIdx.x;   // 256
    const int c   = tid & 31;
    const int ch  = tid >> 5;      // 0..7, each handles NBLK/8 = 64 slots
    float s0 = 0.f, s1 = 0.f, s2 = 0.f, s3 = 0.f;
    for (int b = 0; b < NBLK / 8; b += 4) {
        s0 += ws[(size_t)(ch * (NBLK / 8) + b + 0) * 32 + c];
        s1 += ws[(size_t)(ch * (NBLK / 8) + b + 1) * 32 + c];
        s2 += ws[(size_t)(ch * (NBLK / 8) + b + 2) * 32 + c];
        s3 += ws[(size_t)(ch * (NBLK / 8) + b + 3) * 32 + c];
    }
    partial[ch][c] = (s0 + s1) + (s2 + s3);
    __syncthreads();
    if (tid < 32) {
        float t = 0.f;
        #pragma unroll
        for (int k = 0; k < 8; ++k) t += partial[k][tid];
        col[tid] = t;
    }
    __syncthreads();
    if (tid == 0) {
        float sum = 0.f;
        #pragma unroll
        for (int e = 0; e < N_EXPERT; ++e)
            sum += col[e] * col[16 + e];
        out[4 * N_TOKENS] = sum * (float)N_EXPERT
                          / ((float)N_TOKENS * (float)N_TOKENS);
    }
}

extern "C" void kernel_launch(void* const* d_in, const int* in_sizes, int n_in,
                              void* d_out, int out_size, void* d_ws, size_t ws_size,
                              hipStream_t stream)
{
    const float* inp = (const float*)d_in[0];
    const float* W   = (const float*)d_in[1];
    float* out = (float*)d_out;
    float* ws  = (float*)d_ws;

    gate_kernel<<<NBLK, TPB, 0, stream>>>(inp, W, out, ws);
    loss_kernel<<<1, 256, 0, stream>>>(ws, out);
}

// Round 8
// 37.714 us; speedup vs baseline: 1.1995x; 1.0344x over previous
//
#include <hip/hip_runtime.h>
#include <math.h>

#define N_TOKENS 32768
#define D_MODEL  1024
#define N_EXPERT 16
#define TPB      256
#define NBLK     1024              // blocks (4 concurrent per CU)
#define TOKS     32                // tokens per block (2 batches of 16)
#define BATCH    16

typedef float f32x4 __attribute__((ext_vector_type(4)));
typedef float f32x2 __attribute__((ext_vector_type(2)));

// DPP cross-lane XOR within 16-lane rows (VALU pipe):
//   ^1: quad_perm [1,0,3,2]=0xB1; ^2: quad_perm [2,3,0,1]=0x4E;
//   ^8: row_ror:8 = 0x128 ((i+8) mod 16 == i^8).  (HW-verified rounds 6-7.)
template<int CTRL>
static __device__ __forceinline__ float dpp_xor(float v) {
    return __int_as_float(__builtin_amdgcn_update_dpp(
        0, __float_as_int(v), CTRL, 0xF, 0xF, true));
}

// Packed fp32 dot over 4 dims: v_pk_mul + v_pk_fma + horizontal add.
static __device__ __forceinline__ float dot4pk(f32x4 x, f32x4 w) {
    f32x2 xl = __builtin_shufflevector(x, x, 0, 1);
    f32x2 xh = __builtin_shufflevector(x, x, 2, 3);
    f32x2 wl = __builtin_shufflevector(w, w, 0, 1);
    f32x2 wh = __builtin_shufflevector(w, w, 2, 3);
    f32x2 m, r;
    asm("v_pk_mul_f32 %0, %1, %2" : "=v"(m) : "v"(xl), "v"(wl));
    asm("v_pk_fma_f32 %0, %1, %2, %3" : "=v"(r) : "v"(xh), "v"(wh), "v"(m));
    return r.x + r.y;
}

// d_out layout (float32, concatenated outputs):
//   [0, 65536)       top_k_indices as floats, row-major [N,2]
//   [65536, 131072)  top_k_scores,            row-major [N,2]
//   [131072]         loss scalar
// d_ws: NBLK slots of 32 floats; slot b: [0..15] expert counts, [16..31] prob sums.

__global__ __launch_bounds__(256, 4)
void gate_kernel(const float* __restrict__ inp,
                 const float* __restrict__ W,
                 float* __restrict__ out,
                 float* __restrict__ ws)
{
    const int tid  = threadIdx.x;
    const int wave = tid >> 6;
    const int lane = tid & 63;
    const int p    = lane & 15;               // expert rotation for this lane
    const int d0   = wave * 256 + lane * 4;   // this lane's 4 dims
    const int base = blockIdx.x * TOKS;

    // XOR-rotated W fragment: wreg[j] = W[j^p][d0..d0+3].  After the uniform
    // butterfly, lane ends holding expert p's logit partial.  64 VGPRs.
    f32x4 wreg[N_EXPERT];
    #pragma unroll
    for (int j = 0; j < N_EXPERT; ++j)
        wreg[j] = *reinterpret_cast<const f32x4*>(W + (j ^ p) * D_MODEL + d0);

    __shared__ float lds_part[2][BATCH][4][N_EXPERT];  // double-buffered
    __shared__ float lds_red[4][2][N_EXPERT];          // final cnt/ps reduce

    float cnt_acc = 0.f;
    float ps_acc  = 0.f;

    const float* xptr = inp + (size_t)base * D_MODEL + d0;

#define LOADX(xr, t) xr = *reinterpret_cast<const f32x4*>(xptr + (size_t)(t) * D_MODEL);

    // Select-free transpose-reduce: stage m does b[j] = a[j] + xor_m(a[j^m]).
    // Masks 8,2,1 via DPP; masks 4,16,32 via shfl.  slot = token&15.
#define DOTOK(xv, slot, BUF) do { \
    float a0 =dot4pk(xv,wreg[0]),  a1 =dot4pk(xv,wreg[1]);  \
    float a2 =dot4pk(xv,wreg[2]),  a3 =dot4pk(xv,wreg[3]);  \
    float a4 =dot4pk(xv,wreg[4]),  a5 =dot4pk(xv,wreg[5]);  \
    float a6 =dot4pk(xv,wreg[6]),  a7 =dot4pk(xv,wreg[7]);  \
    float a8 =dot4pk(xv,wreg[8]),  a9 =dot4pk(xv,wreg[9]);  \
    float a10=dot4pk(xv,wreg[10]), a11=dot4pk(xv,wreg[11]); \
    float a12=dot4pk(xv,wreg[12]), a13=dot4pk(xv,wreg[13]); \
    float a14=dot4pk(xv,wreg[14]), a15=dot4pk(xv,wreg[15]); \
    float b0 = a0 + dpp_xor<0x128>(a8);  \
    float b1 = a1 + dpp_xor<0x128>(a9);  \
    float b2 = a2 + dpp_xor<0x128>(a10); \
    float b3 = a3 + dpp_xor<0x128>(a11); \
    float b4 = a4 + dpp_xor<0x128>(a12); \
    float b5 = a5 + dpp_xor<0x128>(a13); \
    float b6 = a6 + dpp_xor<0x128>(a14); \
    float b7 = a7 + dpp_xor<0x128>(a15); \
    float c0 = b0 + __shfl_xor(b4, 4); \
    float c1 = b1 + __shfl_xor(b5, 4); \
    float c2 = b2 + __shfl_xor(b6, 4); \
    float c3 = b3 + __shfl_xor(b7, 4); \
    float d0_ = c0 + dpp_xor<0x4E>(c2); \
    float d1_ = c1 + dpp_xor<0x4E>(c3); \
    float s0  = d0_ + dpp_xor<0xB1>(d1_); \
    s0 += __shfl_xor(s0, 16); \
    s0 += __shfl_xor(s0, 32); \
    if (lane < N_EXPERT) BUF[slot][wave][lane] = s0; \
} while (0)

    // Phase B: 16 tokens x 16 expert-lanes: sum 4 wave partials, top-2
    // merge butterfly ((val desc, idx asc) == jax.lax.top_k), 2-way softmax.
#define PHASEB(BUF, TOKBASE) do { \
    const int tgrp = tid >> 4; \
    const int el   = tid & 15; \
    float v1 = BUF[tgrp][0][el] + BUF[tgrp][1][el] \
             + BUF[tgrp][2][el] + BUF[tgrp][3][el]; \
    int   i1 = el; \
    float v2 = -INFINITY; \
    int   i2 = 0; \
    _Pragma("unroll") \
    for (int m = 1; m <= 8; m <<= 1) { \
        float o1 = __shfl_xor(v1, m); \
        int  oi1 = __shfl_xor(i1, m); \
        float o2 = __shfl_xor(v2, m); \
        int  oi2 = __shfl_xor(i2, m); \
        bool afirst = (v1 > o1) || (v1 == o1 && i1 < oi1); \
        float c1v = afirst ? v1 : o1;   int c1i = afirst ? i1 : oi1; \
        float bv  = afirst ? o1 : v1;   int bi  = afirst ? oi1 : i1; \
        float sv  = afirst ? v2 : o2;   int si  = afirst ? i2 : oi2; \
        bool sgt  = (bv > sv) || (bv == sv && bi < si); \
        v1 = c1v; i1 = c1i; \
        v2 = sgt ? bv : sv;  i2 = sgt ? bi : si; \
    } \
    float tt = expf(v2 - v1); \
    float p1 = 1.f / (1.f + tt); \
    float p2 = tt * p1; \
    const int tok = (TOKBASE) + tgrp; \
    if (el == 0) { \
        *reinterpret_cast<float2*>(out + 2 * tok) = \
            make_float2((float)i1, (float)i2); \
        *reinterpret_cast<float2*>(out + 2 * N_TOKENS + 2 * tok) = \
            make_float2(p1, p2); \
    } \
    cnt_acc += (el == i1 ? 1.f : 0.f) + (el == i2 ? 1.f : 0.f); \
    ps_acc  += (el == i1 ? p1  : 0.f) + (el == i2 ? p2  : 0.f); \
} while (0)

    f32x4 x0, x1, x2, x3;

    // ---- Batch 0: tokens 0..15 ----
    LOADX(x0, 0) LOADX(x1, 1) LOADX(x2, 2) LOADX(x3, 3)
    for (int g = 0; g < 3; ++g) {
        const int t = g * 4;
        DOTOK(x0, t + 0, lds_part[0]); LOADX(x0, t + 4)
        DOTOK(x1, t + 1, lds_part[0]); LOADX(x1, t + 5)
        DOTOK(x2, t + 2, lds_part[0]); LOADX(x2, t + 6)
        DOTOK(x3, t + 3, lds_part[0]); LOADX(x3, t + 7)
    }
    // tail of batch 0: issue batch-1 prefetch loads BEFORE the barrier so
    // their latency hides under phase B (T14 issue-early pattern).
    DOTOK(x0, 12, lds_part[0]); LOADX(x0, 16)
    DOTOK(x1, 13, lds_part[0]); LOADX(x1, 17)
    DOTOK(x2, 14, lds_part[0]); LOADX(x2, 18)
    DOTOK(x3, 15, lds_part[0]); LOADX(x3, 19)

    __syncthreads();
    PHASEB(lds_part[0], base);

    // ---- Batch 1: tokens 16..31 (writes buffer 1; no barrier needed after
    // phase B since it reads buffer 0) ----
    for (int g = 0; g < 3; ++g) {
        const int t = 16 + g * 4;
        DOTOK(x0, (t + 0) & 15, lds_part[1]); LOADX(x0, t + 4)
        DOTOK(x1, (t + 1) & 15, lds_part[1]); LOADX(x1, t + 5)
        DOTOK(x2, (t + 2) & 15, lds_part[1]); LOADX(x2, t + 6)
        DOTOK(x3, (t + 3) & 15, lds_part[1]); LOADX(x3, t + 7)
    }
    DOTOK(x0, 12, lds_part[1]);
    DOTOK(x1, 13, lds_part[1]);
    DOTOK(x2, 14, lds_part[1]);
    DOTOK(x3, 15, lds_part[1]);

    __syncthreads();
    PHASEB(lds_part[1], base + 16);

    // Final cnt/ps reduction: lanes l, l^16, l^32 share el -> 2 shuffles,
    // then one cross-wave LDS pass.
    cnt_acc += __shfl_xor(cnt_acc, 16); cnt_acc += __shfl_xor(cnt_acc, 32);
    ps_acc  += __shfl_xor(ps_acc, 16);  ps_acc  += __shfl_xor(ps_acc, 32);
    __syncthreads();   // lds_part reuse hazard is gone; protect lds_red region
    if (lane < N_EXPERT) {
        lds_red[wave][0][lane] = cnt_acc;
        lds_red[wave][1][lane] = ps_acc;
    }
    __syncthreads();
    if (tid < 32) {
        const int el = tid & 15;
        const int which = tid >> 4;   // 0 = cnt, 1 = ps
        float v = lds_red[0][which][el] + lds_red[1][which][el]
                + lds_red[2][which][el] + lds_red[3][which][el];
        ws[blockIdx.x * 32 + tid] = v;
    }
#undef LOADX
#undef DOTOK
#undef PHASEB
}

__global__ void loss_kernel(const float* __restrict__ ws, float* __restrict__ out)
{
    // Reduce NBLK x 32 partial slots, then dot counts x prob-sums.
    __shared__ float partial[8][32];
    __shared__ float col[32];
    const int tid = threadIdx.x;   // 256
    const int c   = tid & 31;
    const int ch  = tid >> 5;      // 0..7, each handles NBLK/8 = 128 slots
    float s0 = 0.f, s1 = 0.f, s2 = 0.f, s3 = 0.f;
    for (int b = 0; b < NBLK / 8; b += 4) {
        s0 += ws[(size_t)(ch * (NBLK / 8) + b + 0) * 32 + c];
        s1 += ws[(size_t)(ch * (NBLK / 8) + b + 1) * 32 + c];
        s2 += ws[(size_t)(ch * (NBLK / 8) + b + 2) * 32 + c];
        s3 += ws[(size_t)(ch * (NBLK / 8) + b + 3) * 32 + c];
    }
    partial[ch][c] = (s0 + s1) + (s2 + s3);
    __syncthreads();
    if (tid < 32) {
        float t = 0.f;
        #pragma unroll
        for (int k = 0; k < 8; ++k) t += partial[k][tid];
        col[tid] = t;
    }
    __syncthreads();
    if (tid == 0) {
        float sum = 0.f;
        #pragma unroll
        for (int e = 0; e < N_EXPERT; ++e)
            sum += col[e] * col[16 + e];
        out[4 * N_TOKENS] = sum * (float)N_EXPERT
                          / ((float)N_TOKENS * (float)N_TOKENS);
    }
}

extern "C" void kernel_launch(void* const* d_in, const int* in_sizes, int n_in,
                              void* d_out, int out_size, void* d_ws, size_t ws_size,
                              hipStream_t stream)
{
    const float* inp = (const float*)d_in[0];
    const float* W   = (const float*)d_in[1];
    float* out = (float*)d_out;
    float* ws  = (float*)d_ws;

    gate_kernel<<<NBLK, TPB, 0, stream>>>(inp, W, out, ws);
    loss_kernel<<<1, 256, 0, stream>>>(ws, out);
}